// Round 6
// baseline (112.054 us; speedup 1.0000x reference)
//
#include <hip/hip_runtime.h>

#define N2   8192
#define N    4096
#define LOGN 12
#define F_TOT 4097   // N2/2 + 1
#define FP    4128   // padded f-stride (float2) = 129*32 (block-tile padded)
#define D    128
#define K    16
#define B    2
#define KD   (K * D)
#define PI_F 3.14159265358979323846f

typedef __bf16 bf16x8 __attribute__((ext_vector_type(8)));
typedef float  f32x4  __attribute__((ext_vector_type(4)));

// LDS index swizzle for FFT bit-reverse patterns.
__device__ __forceinline__ int swz(int w, bool on) {
  return on ? (w ^ ((w >> 6) & 31)) : w;
}

// In-place radix-2 DIT FFT on bit-reverse-loaded data in LDS.
template<bool SWZ>
__device__ __forceinline__ void fft_lds(float* re, float* im, int tid, int nthr, float sign) {
  for (int s = 0; s < LOGN; ++s) {
    int len = 1 << s;
    for (int t = tid; t < (N >> 1); t += nthr) {
      int j = t & (len - 1);
      int base = ((t >> s) << (s + 1)) + j;
      int i0 = swz(base, SWZ), i1 = swz(base + len, SWZ);
      float ang = sign * PI_F * (float)j / (float)len;
      float wi, wr;
      __sincosf(ang, &wi, &wr);
      float ar = re[i0], ai = im[i0];
      float br = re[i1], bi = im[i1];
      float tr = wr * br - wi * bi;
      float ti = wr * bi + wi * br;
      re[i0] = ar + tr;  im[i0] = ai + ti;
      re[i1] = ar - tr;  im[i1] = ai - ti;
    }
    __syncthreads();
  }
}

// Forward rfft(n=8192) of real length-4096 signals via 4096-pt complex FFT.
// Blocks 0..255: x (b,d). 256..271: filters (k). 272..303: M->bf16 re-layout
// Mt[half][kd8][e][8] with kd8 = k*16 + d/8 (lane-contiguous B-frag loads).
__global__ __launch_bounds__(512) void fwd_fft(const float* __restrict__ x,
                                               const float* __restrict__ filt,
                                               const float* __restrict__ Mp,
                                               const float* __restrict__ Mm,
                                               float2* __restrict__ Uf,
                                               float2* __restrict__ Vf,
                                               __bf16* __restrict__ Mt) {
  __shared__ float re[N];
  __shared__ float im[N];
  const int tid = threadIdx.x;
  const int sig = blockIdx.x;

  if (sig >= B * D + K) {          // ---- M prep path ----
    const int pid = sig - (B * D + K);
    const int k = pid & 15, h = pid >> 4;
    const float* src = (h ? Mm : Mp) + (size_t)k * D * D;
    for (int d0 = 0; d0 < D; d0 += 16) {
      for (int i = tid; i < 16 * D; i += 512) re[i] = src[(size_t)d0 * D + i];
      __syncthreads();
      if (tid < 256) {
        const int e = tid >> 1, c0 = (tid & 1) * 8;
        bf16x8 w;
#pragma unroll
        for (int j = 0; j < 8; ++j) w[j] = (__bf16)re[(c0 + j) * D + e];
        const size_t kd8 = (size_t)h * 256 + k * 16 + ((d0 + c0) >> 3);
        *(bf16x8*)(Mt + (kd8 * D + e) * 8) = w;
      }
      __syncthreads();
    }
    return;
  }

  const float* in; int istride; float2* outp; int ostride;
  if (sig < B * D) {
    int b = sig >> 7, d = sig & (D - 1);
    in = x + (size_t)b * N * D + d;              istride = D;
    outp = Uf + (size_t)b * F_TOT * D + d;       ostride = D;
  } else {
    int k = sig - B * D;
    in = filt + k;                               istride = K;
    outp = Vf + k;                               ostride = K;
  }
  for (int i = tid; i < N; i += 512) {
    int m = __brev(i) >> (32 - LOGN);
    float vr = 0.f, vi = 0.f;
    if (m < (N >> 1)) {
      vr = in[(size_t)(2 * m) * istride];
      vi = in[(size_t)(2 * m + 1) * istride];
    }
    re[i] = vr; im[i] = vi;
  }
  __syncthreads();
  fft_lds<false>(re, im, tid, 512, -1.0f);
  for (int f = tid; f <= N; f += 512) {
    int f2 = f & (N - 1);
    int fn = (N - f) & (N - 1);
    float zr = re[f2], zi = im[f2];
    float nr = re[fn], ni = im[fn];
    float Er = 0.5f * (zr + nr), Ei = 0.5f * (zi - ni);
    float Or = 0.5f * (zi + ni), Oi = -0.5f * (zr - nr);
    float ang = -PI_F * (float)f / (float)N;
    float wi, wr; __sincosf(ang, &wi, &wr);
    outp[(size_t)f * ostride] = make_float2(Er + wr * Or - wi * Oi,
                                            Ei + wr * Oi + wi * Or);
  }
}

// MFMA middle. Wave = TWO 16-row subtiles (8 f x {b,comp}) x 128 e: each
// B-frag load feeds 2 MFMAs (halves L1 B-traffic vs 1 subtile).
// Block = 4 waves = 32 f. Grid (129, half, NKS).
// Gt[((part*B+b)*D + e)*FP + f], part = half*NKS + ks.
template<int NKS>
__global__ __launch_bounds__(256, 3) void middle_mfma(const float2* __restrict__ Uf,
                                                      const float2* __restrict__ Vf,
                                                      const __bf16* __restrict__ Mt,
                                                      float2* __restrict__ Gt) {
  __shared__ float2 tr[128 * 35];
  const int tid = threadIdx.x;
  const int l = tid & 63, wave = tid >> 6;
  const int half = blockIdx.y, ks = blockIdx.z;
  const int fw0 = blockIdx.x * 32 + wave * 8;
  const int rowsub = l & 15, g = l >> 4;
  const int fo = rowsub >> 2, bb = (rowsub >> 1) & 1, comp = rowsub & 1;
  int fs0 = fw0 + fo;     if (fs0 > N) fs0 = N;
  int fs1 = fw0 + 4 + fo; if (fs1 > N) fs1 = N;

  const float4* u0p = (const float4*)(Uf + ((size_t)bb * F_TOT + fs0) * D);
  const float4* u1p = (const float4*)(Uf + ((size_t)bb * F_TOT + fs1) * D);
  const float2* v0p = Vf + (size_t)(half ? N - fs0 : fs0) * K;
  const float2* v1p = Vf + (size_t)(half ? N - fs1 : fs1) * K;
  const float vsgn = half ? -1.f : 1.f;

  constexpr int NK = K / NKS;
  float c0[2][NK], c1[2][NK];
#pragma unroll
  for (int k8 = 0; k8 < NK; ++k8) {
    float2 v = v0p[ks * NK + k8];
    float vi = vsgn * v.y;
    c0[0][k8] = comp ? vi : v.x;
    c1[0][k8] = comp ? v.x : -vi;
    v = v1p[ks * NK + k8];
    vi = vsgn * v.y;
    c0[1][k8] = comp ? vi : v.x;
    c1[1][k8] = comp ? v.x : -vi;
  }

  f32x4 acc[2][8];
#pragma unroll
  for (int s = 0; s < 2; ++s)
#pragma unroll
    for (int nt = 0; nt < 8; ++nt) acc[s][nt] = (f32x4)0.f;

  const __bf16* mtb = Mt + (((size_t)half * 256 + (size_t)ks * NK * 16) * D + rowsub) * 8;

#pragma unroll
  for (int ds = 0; ds < 4; ++ds) {
    const int q = ds * 16 + g * 4;
    const float4 ua0 = u0p[q], ub0 = u0p[q + 1], uc0 = u0p[q + 2], ud0 = u0p[q + 3];
    const float4 ua1 = u1p[q], ub1 = u1p[q + 1], uc1 = u1p[q + 2], ud1 = u1p[q + 3];
#pragma unroll
    for (int k8 = 0; k8 < NK; ++k8) {
      bf16x8 a0, a1;
      a0[0] = (__bf16)fmaf(c1[0][k8], ua0.y, c0[0][k8] * ua0.x);
      a0[1] = (__bf16)fmaf(c1[0][k8], ua0.w, c0[0][k8] * ua0.z);
      a0[2] = (__bf16)fmaf(c1[0][k8], ub0.y, c0[0][k8] * ub0.x);
      a0[3] = (__bf16)fmaf(c1[0][k8], ub0.w, c0[0][k8] * ub0.z);
      a0[4] = (__bf16)fmaf(c1[0][k8], uc0.y, c0[0][k8] * uc0.x);
      a0[5] = (__bf16)fmaf(c1[0][k8], uc0.w, c0[0][k8] * uc0.z);
      a0[6] = (__bf16)fmaf(c1[0][k8], ud0.y, c0[0][k8] * ud0.x);
      a0[7] = (__bf16)fmaf(c1[0][k8], ud0.w, c0[0][k8] * ud0.z);
      a1[0] = (__bf16)fmaf(c1[1][k8], ua1.y, c0[1][k8] * ua1.x);
      a1[1] = (__bf16)fmaf(c1[1][k8], ua1.w, c0[1][k8] * ua1.z);
      a1[2] = (__bf16)fmaf(c1[1][k8], ub1.y, c0[1][k8] * ub1.x);
      a1[3] = (__bf16)fmaf(c1[1][k8], ub1.w, c0[1][k8] * ub1.z);
      a1[4] = (__bf16)fmaf(c1[1][k8], uc1.y, c0[1][k8] * uc1.x);
      a1[5] = (__bf16)fmaf(c1[1][k8], uc1.w, c0[1][k8] * uc1.z);
      a1[6] = (__bf16)fmaf(c1[1][k8], ud1.y, c0[1][k8] * ud1.x);
      a1[7] = (__bf16)fmaf(c1[1][k8], ud1.w, c0[1][k8] * ud1.z);
      const __bf16* bp = mtb + ((size_t)(k8 * 16 + ds * 4 + g) * D) * 8;
#pragma unroll
      for (int nt = 0; nt < 8; ++nt) {
        bf16x8 bf = *(const bf16x8*)(bp + nt * 16 * 8);
        acc[0][nt] = __builtin_amdgcn_mfma_f32_16x16x32_bf16(a0, bf, acc[0][nt], 0, 0, 0);
        acc[1][nt] = __builtin_amdgcn_mfma_f32_16x16x32_bf16(a1, bf, acc[1][nt], 0, 0, 0);
      }
    }
  }

  // ---- epilogue: two passes (b = 0,1), LDS transpose -> 256B-contiguous rows
  const int part = half * NKS + ks;
  const int fcol0 = wave * 8;
#pragma unroll
  for (int bo = 0; bo < 2; ++bo) {
    if (bo) __syncthreads();
#pragma unroll
    for (int s = 0; s < 2; ++s)
#pragma unroll
      for (int nt = 0; nt < 8; ++nt) {
        const int e = nt * 16 + rowsub;
        tr[e * 35 + fcol0 + s * 4 + g] =
            make_float2(acc[s][nt][bo * 2], acc[s][nt][bo * 2 + 1]);
      }
    __syncthreads();
    float2* gb = Gt + (((size_t)part * B + bo) * D) * FP + (size_t)blockIdx.x * 32;
    const int rr = tid >> 4, fc = (tid & 15) * 2;
#pragma unroll
    for (int it = 0; it < 8; ++it) {
      const int e = it * 16 + rr;
      float2 v0 = tr[e * 35 + fc], v1 = tr[e * 35 + fc + 1];
      *(float4*)(gb + (size_t)e * FP + fc) = make_float4(v0.x, v0.y, v1.x, v1.y);
    }
  }
}

// irfft(n=8192) per (b,e): coalesced row reads of Gt, (kk, N-kk) pairs share
// one twiddle, swizzled LDS, 512 threads. NSLAB partial sums unrolled.
template<int NSLAB>
__global__ __launch_bounds__(512) void inv_fft(const float2* __restrict__ Gt,
                                               float* __restrict__ out) {
  __shared__ float re[N];
  __shared__ float im[N];
  const int tid = threadIdx.x;
  const int sig = blockIdx.x;
  const int b = sig >> 7, e = sig & (D - 1);
  const float2* g0 = Gt + ((size_t)b * D + e) * FP;
  const size_t pstr = (size_t)B * D * FP;

  for (int kk = tid; kk <= (N >> 1); kk += 512) {
    float2 Xk = make_float2(0.f, 0.f), Xn = make_float2(0.f, 0.f);
#pragma unroll
    for (int p = 0; p < NSLAB; ++p) {
      float2 t1 = g0[p * pstr + kk];
      float2 t2 = g0[p * pstr + (N - kk)];
      Xk.x += t1.x; Xk.y += t1.y;
      Xn.x += t2.x; Xn.y += t2.y;
    }
    float Er = 0.5f * (Xk.x + Xn.x), Ei = 0.5f * (Xk.y - Xn.y);
    float Dr = 0.5f * (Xk.x - Xn.x), Di = 0.5f * (Xk.y + Xn.y);
    float ang = PI_F * (float)kk / (float)N;
    float wi, wr; __sincosf(ang, &wi, &wr);
    float Or = Dr * wr - Di * wi;
    float Oi = Dr * wi + Di * wr;
    int d1 = swz(__brev(kk) >> (32 - LOGN), true);
    re[d1] = Er - Oi; im[d1] = Ei + Or;
    if (kk != 0 && kk != (N >> 1)) {
      int d2 = swz(__brev(N - kk) >> (32 - LOGN), true);
      re[d2] = Er + Oi; im[d2] = -Ei + Or;   // conj-pair: same twiddle
    }
  }
  __syncthreads();
  fft_lds<true>(re, im, tid, 512, +1.0f);
  const float scale = 1.0f / (float)N;
  float* ob = out + (size_t)b * N * D + e;
  for (int m = tid; m < (N >> 1); m += 512) {
    int i0 = swz(m, true);
    ob[(size_t)(2 * m) * D]     = re[i0] * scale;
    ob[(size_t)(2 * m + 1) * D] = im[i0] * scale;
  }
}

extern "C" void kernel_launch(void* const* d_in, const int* in_sizes, int n_in,
                              void* d_out, int out_size, void* d_ws, size_t ws_size,
                              hipStream_t stream) {
  const float* x  = (const float*)d_in[0];
  const float* fl = (const float*)d_in[1];
  const float* Mp = (const float*)d_in[2];
  const float* Mm = (const float*)d_in[3];
  float* out = (float*)d_out;

  const size_t uf_n  = (size_t)B * F_TOT * D;   // float2
  const size_t vf_n  = (size_t)F_TOT * K;       // float2
  const size_t gsl_n = (size_t)B * D * FP;      // float2 per G slab
  const size_t mt_b  = (size_t)2 * D * KD * sizeof(__bf16);

  const size_t need4 = (uf_n + vf_n + 8 * gsl_n) * sizeof(float2) + mt_b;
  const size_t need2 = (uf_n + vf_n + 4 * gsl_n) * sizeof(float2) + mt_b;
  const int KS = (ws_size >= need4) ? 4 : (ws_size >= need2) ? 2 : 1;

  float2* Uf = (float2*)d_ws;
  float2* Vf = Uf + uf_n;
  float2* Gt = Vf + vf_n;
  __bf16* Mt = (__bf16*)(Gt + (size_t)2 * KS * gsl_n);

  fwd_fft<<<B * D + K + 32, 512, 0, stream>>>(x, fl, Mp, Mm, Uf, Vf, Mt);
  if (KS == 4) {
    middle_mfma<4><<<dim3(129, 2, 4), 256, 0, stream>>>(Uf, Vf, Mt, Gt);
    inv_fft<8><<<B * D, 512, 0, stream>>>(Gt, out);
  } else if (KS == 2) {
    middle_mfma<2><<<dim3(129, 2, 2), 256, 0, stream>>>(Uf, Vf, Mt, Gt);
    inv_fft<4><<<B * D, 512, 0, stream>>>(Gt, out);
  } else {
    middle_mfma<1><<<dim3(129, 2, 1), 256, 0, stream>>>(Uf, Vf, Mt, Gt);
    inv_fft<2><<<B * D, 512, 0, stream>>>(Gt, out);
  }
}

// Round 7
// 104.342 us; speedup vs baseline: 1.0739x; 1.0739x over previous
//
#include <hip/hip_runtime.h>

#define N2   8192
#define N    4096
#define LOGN 12
#define F_TOT 4097   // N2/2 + 1
#define FP    4112   // padded f-stride (float2), 16-aligned
#define D    128
#define K    16
#define B    2
#define PI_F 3.14159265358979323846f

typedef __bf16 bf16x8 __attribute__((ext_vector_type(8)));
typedef float  f32x4  __attribute__((ext_vector_type(4)));

__device__ __forceinline__ void gload_lds16(const void* g, void* l) {
  __builtin_amdgcn_global_load_lds((const __attribute__((address_space(1))) uint32_t*)g,
                                   (__attribute__((address_space(3))) uint32_t*)l, 16, 0, 0);
}

// LDS index swizzle for FFT bit-reverse patterns.
__device__ __forceinline__ int swz(int w, bool on) {
  return on ? (w ^ ((w >> 6) & 31)) : w;
}

// In-place radix-2 DIT FFT on bit-reverse-loaded data in LDS.
template<bool SWZ>
__device__ __forceinline__ void fft_lds(float* re, float* im, int tid, int nthr, float sign) {
  for (int s = 0; s < LOGN; ++s) {
    int len = 1 << s;
    for (int t = tid; t < (N >> 1); t += nthr) {
      int j = t & (len - 1);
      int base = ((t >> s) << (s + 1)) + j;
      int i0 = swz(base, SWZ), i1 = swz(base + len, SWZ);
      float ang = sign * PI_F * (float)j / (float)len;
      float wi, wr;
      __sincosf(ang, &wi, &wr);
      float ar = re[i0], ai = im[i0];
      float br = re[i1], bi = im[i1];
      float tr = wr * br - wi * bi;
      float ti = wr * bi + wi * br;
      re[i0] = ar + tr;  im[i0] = ai + ti;
      re[i1] = ar - tr;  im[i1] = ai - ti;
    }
    __syncthreads();
  }
}

// Forward rfft(n=8192) of real length-4096 signals via 4096-pt complex FFT.
// Blocks 0..255: x (b,d). 256..271: filters (k). 272..303: M->bf16 re-layout
// Mt[pm][eq][k][kd8(16)][el(32)][8]: per-(pm,eq,k) contiguous 8KB tile.
__global__ __launch_bounds__(512) void fwd_fft(const float* __restrict__ x,
                                               const float* __restrict__ filt,
                                               const float* __restrict__ Mp,
                                               const float* __restrict__ Mm,
                                               float2* __restrict__ Uf,
                                               float2* __restrict__ Vf,
                                               __bf16* __restrict__ Mt) {
  __shared__ float re[N];
  __shared__ float im[N];
  const int tid = threadIdx.x;
  const int sig = blockIdx.x;

  if (sig >= B * D + K) {          // ---- M prep path ----
    const int pid = sig - (B * D + K);
    const int k = pid & 15, h = pid >> 4;
    const float* src = (h ? Mm : Mp) + (size_t)k * D * D;
    for (int d0 = 0; d0 < D; d0 += 16) {
      for (int i = tid; i < 16 * D; i += 512) re[i] = src[(size_t)d0 * D + i];
      __syncthreads();
      if (tid < 256) {
        const int e = tid >> 1, c0 = (tid & 1) * 8;
        bf16x8 w;
#pragma unroll
        for (int j = 0; j < 8; ++j) w[j] = (__bf16)re[(c0 + j) * D + e];
        const int eq = e >> 5, el = e & 31;
        const size_t kd8 = (size_t)(d0 + c0) >> 3;
        *(bf16x8*)(Mt + (((((size_t)h * 4 + eq) * K + k) * 16 + kd8) * 32 + el) * 8) = w;
      }
      __syncthreads();
    }
    return;
  }

  const float* in; int istride; float2* outp; int ostride;
  if (sig < B * D) {
    int b = sig >> 7, d = sig & (D - 1);
    in = x + (size_t)b * N * D + d;              istride = D;
    outp = Uf + (size_t)b * F_TOT * D + d;       ostride = D;
  } else {
    int k = sig - B * D;
    in = filt + k;                               istride = K;
    outp = Vf + k;                               ostride = K;
  }
  for (int i = tid; i < N; i += 512) {
    int m = __brev(i) >> (32 - LOGN);
    float vr = 0.f, vi = 0.f;
    if (m < (N >> 1)) {
      vr = in[(size_t)(2 * m) * istride];
      vi = in[(size_t)(2 * m + 1) * istride];
    }
    re[i] = vr; im[i] = vi;
  }
  __syncthreads();
  fft_lds<false>(re, im, tid, 512, -1.0f);
  for (int f = tid; f <= N; f += 512) {
    int f2 = f & (N - 1);
    int fn = (N - f) & (N - 1);
    float zr = re[f2], zi = im[f2];
    float nr = re[fn], ni = im[fn];
    float Er = 0.5f * (zr + nr), Ei = 0.5f * (zi - ni);
    float Or = 0.5f * (zi + ni), Oi = -0.5f * (zr - nr);
    float ang = -PI_F * (float)f / (float)N;
    float wi, wr; __sincosf(ang, &wi, &wr);
    outp[(size_t)f * ostride] = make_float2(Er + wr * Or - wi * Oi,
                                            Ei + wr * Oi + wi * Or);
  }
}

// MFMA middle. A-rows = (f, b, re/im) built from U ONCE (k-invariant, in
// registers). Per k: MFMA partial products vs Mp/Mm (LDS double-buffered),
// then VALU fixup applies V coefficients and accumulates G = G+ + G-.
// Wave = 4 subtiles (16 f) x 16 e. Block = 32 f x 32 e. Grid (129, 4).
__global__ __launch_bounds__(256, 2) void middle_mfma(const float2* __restrict__ Uf,
                                                      const float2* __restrict__ Vf,
                                                      const __bf16* __restrict__ Mt,
                                                      float2* __restrict__ Gt) {
  __shared__ __bf16 bbuf[2][2][4096];   // [buf][pm][16 kd8][32 el][8] = 32 KB
  __shared__ float2 tr[64][33];
  const int tid = threadIdx.x;
  const int l = tid & 63, w = tid >> 6;
  const int l15 = l & 15, g = l >> 4;
  const int fg = w >> 1, eg = w & 1;
  const int eq = blockIdx.y;
  const int fx = blockIdx.x * 32;
  const int fo = l15 >> 2, bb = (l15 >> 1) & 1, ri = l15 & 1;

  // issue k=0 staging first so it overlaps the A-frag build
  auto STAGE = [&](int buf, int kk) {
#pragma unroll
    for (int i = 0; i < 4; ++i) {
      const int oe = w * 2048 + i * 512;          // elem offset in [2][4096]
      const int pm = oe >> 12, within = oe & 4095;
      const __bf16* src = Mt + ((((size_t)pm * 4 + eq) * K + kk) * 4096) + within + l * 8;
      gload_lds16((const void*)src, (void*)(&bbuf[buf][0][0] + oe));
    }
  };
  STAGE(0, 0);

  // ---- k-invariant A fragments: A[s][ds], row = l15, kelem = g*8+j -> d = ds*32+g*8+j
  bf16x8 A[4][4];
#pragma unroll
  for (int s = 0; s < 4; ++s) {
    int f = fx + fg * 16 + s * 4 + fo; if (f > N) f = N;
    const float4* urow = (const float4*)(Uf + ((size_t)bb * F_TOT + f) * D);
#pragma unroll
    for (int ds = 0; ds < 4; ++ds) {
      const float4* p = urow + (ds * 32 + g * 8) / 2;
      float4 q0 = p[0], q1 = p[1], q2 = p[2], q3 = p[3];
      bf16x8 a;
      a[0] = (__bf16)(ri ? q0.y : q0.x);
      a[1] = (__bf16)(ri ? q0.w : q0.z);
      a[2] = (__bf16)(ri ? q1.y : q1.x);
      a[3] = (__bf16)(ri ? q1.w : q1.z);
      a[4] = (__bf16)(ri ? q2.y : q2.x);
      a[5] = (__bf16)(ri ? q2.w : q2.z);
      a[6] = (__bf16)(ri ? q3.y : q3.x);
      a[7] = (__bf16)(ri ? q3.w : q3.z);
      A[s][ds] = a;
    }
  }

  f32x4 acc[4];
#pragma unroll
  for (int s = 0; s < 4; ++s) acc[s] = (f32x4)0.f;

  asm volatile("s_waitcnt vmcnt(0)" ::: "memory");
  __syncthreads();

  for (int k = 0; k < K; ++k) {
    if (k + 1 < K) STAGE((k + 1) & 1, k + 1);
    const __bf16* bufc = &bbuf[k & 1][0][0];

    float2 vp[4], vm[4];
#pragma unroll
    for (int s = 0; s < 4; ++s) {
      int fc = fx + fg * 16 + s * 4 + g; if (fc > N) fc = N;
      vp[s] = Vf[(size_t)fc * K + k];
      vm[s] = Vf[(size_t)(N - fc) * K + k];
    }
#pragma unroll
    for (int pm = 0; pm < 2; ++pm) {
      f32x4 P[4];
#pragma unroll
      for (int ds = 0; ds < 4; ++ds) {
        bf16x8 bf = *(const bf16x8*)(bufc + pm * 4096 +
                                     (((ds * 4 + g) * 32 + eg * 16 + l15) * 8));
#pragma unroll
        for (int s = 0; s < 4; ++s) {
          f32x4 cin = (ds == 0) ? (f32x4)0.f : P[s];
          P[s] = __builtin_amdgcn_mfma_f32_16x16x32_bf16(A[s][ds], bf, cin, 0, 0, 0);
        }
      }
#pragma unroll
      for (int s = 0; s < 4; ++s) {
        const float vr = pm ? vm[s].x : vp[s].x;
        const float vy = pm ? vm[s].y : vp[s].y;
        if (pm == 0) {   // G += (vr + i·vy)·(PR + i·PI)
          acc[s][0] += vr * P[s][0] - vy * P[s][1];
          acc[s][1] += vy * P[s][0] + vr * P[s][1];
          acc[s][2] += vr * P[s][2] - vy * P[s][3];
          acc[s][3] += vy * P[s][2] + vr * P[s][3];
        } else {         // G += conj(vr + i·vy)·(PR + i·PI)
          acc[s][0] += vr * P[s][0] + vy * P[s][1];
          acc[s][1] += vr * P[s][1] - vy * P[s][0];
          acc[s][2] += vr * P[s][2] + vy * P[s][3];
          acc[s][3] += vr * P[s][3] - vy * P[s][2];
        }
      }
    }
    asm volatile("s_waitcnt vmcnt(0)" ::: "memory");
    __syncthreads();
  }

  // ---- epilogue: LDS transpose -> coalesced Gt rows (f-contiguous)
#pragma unroll
  for (int s = 0; s < 4; ++s) {
    const int fl = fg * 16 + s * 4 + g;
    const int el = eg * 16 + l15;
    tr[el][fl]      = make_float2(acc[s][0], acc[s][1]);
    tr[32 + el][fl] = make_float2(acc[s][2], acc[s][3]);
  }
  __syncthreads();
#pragma unroll
  for (int p = 0; p < 4; ++p) {
    const int row = p * 16 + (tid >> 4);          // row = bo*32 + e_local
    const int bo = row >> 5, e_gl = eq * 32 + (row & 31);
    const int c = (tid & 15) * 2;
    const int fgl = fx + c;
    if (fgl < F_TOT) {
      float2 v0 = tr[row][c], v1 = tr[row][c + 1];
      *(float4*)&Gt[((size_t)bo * D + e_gl) * FP + fgl] = make_float4(v0.x, v0.y, v1.x, v1.y);
    }
  }
}

// irfft(n=8192) per (b,e): coalesced row reads of Gt (single slab),
// (kk, N-kk) pairs share one twiddle, swizzled LDS, 512 threads.
__global__ __launch_bounds__(512) void inv_fft(const float2* __restrict__ Gt,
                                               float* __restrict__ out) {
  __shared__ float re[N];
  __shared__ float im[N];
  const int tid = threadIdx.x;
  const int sig = blockIdx.x;
  const int b = sig >> 7, e = sig & (D - 1);
  const float2* g0 = Gt + ((size_t)b * D + e) * FP;

  for (int kk = tid; kk <= (N >> 1); kk += 512) {
    float2 Xk = g0[kk];
    float2 Xn = g0[N - kk];
    float Er = 0.5f * (Xk.x + Xn.x), Ei = 0.5f * (Xk.y - Xn.y);
    float Dr = 0.5f * (Xk.x - Xn.x), Di = 0.5f * (Xk.y + Xn.y);
    float ang = PI_F * (float)kk / (float)N;
    float wi, wr; __sincosf(ang, &wi, &wr);
    float Or = Dr * wr - Di * wi;
    float Oi = Dr * wi + Di * wr;
    int d1 = swz(__brev(kk) >> (32 - LOGN), true);
    re[d1] = Er - Oi; im[d1] = Ei + Or;
    if (kk != 0 && kk != (N >> 1)) {
      int d2 = swz(__brev(N - kk) >> (32 - LOGN), true);
      re[d2] = Er + Oi; im[d2] = -Ei + Or;   // conj-pair: same twiddle
    }
  }
  __syncthreads();
  fft_lds<true>(re, im, tid, 512, +1.0f);
  const float scale = 1.0f / (float)N;
  float* ob = out + (size_t)b * N * D + e;
  for (int m = tid; m < (N >> 1); m += 512) {
    int i0 = swz(m, true);
    ob[(size_t)(2 * m) * D]     = re[i0] * scale;
    ob[(size_t)(2 * m + 1) * D] = im[i0] * scale;
  }
}

extern "C" void kernel_launch(void* const* d_in, const int* in_sizes, int n_in,
                              void* d_out, int out_size, void* d_ws, size_t ws_size,
                              hipStream_t stream) {
  const float* x  = (const float*)d_in[0];
  const float* fl = (const float*)d_in[1];
  const float* Mp = (const float*)d_in[2];
  const float* Mm = (const float*)d_in[3];
  float* out = (float*)d_out;

  const size_t uf_n  = (size_t)B * F_TOT * D;   // float2
  const size_t vf_n  = (size_t)F_TOT * K;       // float2
  const size_t gt_n  = (size_t)B * D * FP;      // float2 (single slab)

  float2* Uf = (float2*)d_ws;
  float2* Vf = Uf + uf_n;
  float2* Gt = Vf + vf_n;
  __bf16* Mt = (__bf16*)(Gt + gt_n);            // 2*4*16*4096 bf16 = 1 MB

  fwd_fft<<<B * D + K + 32, 512, 0, stream>>>(x, fl, Mp, Mm, Uf, Vf, Mt);
  middle_mfma<<<dim3(129, 4), 256, 0, stream>>>(Uf, Vf, Mt, Gt);
  inv_fft<<<B * D, 512, 0, stream>>>(Gt, out);
}